// Round 17
// baseline (221.922 us; speedup 1.0000x reference)
//
#include <hip/hip_runtime.h>
#include <math.h>

// B=4, L=1024, D=512, H=8, d=64
#define L_ 1024
#define D_ 512

typedef _Float16 half8 __attribute__((ext_vector_type(8)));
typedef _Float16 half4v __attribute__((ext_vector_type(4)));
typedef _Float16 half2v __attribute__((ext_vector_type(2)));
typedef float floatx4 __attribute__((ext_vector_type(4)));

#define QK_PITCH 136   // halves/row (272B): proven conflict-free residue (r10)

// S layout is Q-TILED: S[bh(32)][q(8)][l(1024)][mi(128)] (halves)
//   addr = bh<<20 | q*131072 + l*128 + mi      (m = q*128 + mi)
#define EOFF(kc) ((size_t)((kc) >> 2) * 131072 + (size_t)(((kc) & 3) * 32))

// load 8 consecutive fp32 and convert to half8 (same rounding the old prep
// used -> bitwise-identical MFMA inputs)
__device__ __forceinline__ half8 ldcvt8(const float* __restrict__ p)
{
    float4 v0 = *(const float4*)p;
    float4 v1 = *(const float4*)(p + 4);
    half8 h;
    h[0] = (_Float16)v0.x; h[1] = (_Float16)v0.y;
    h[2] = (_Float16)v0.z; h[3] = (_Float16)v0.w;
    h[4] = (_Float16)v1.x; h[5] = (_Float16)v1.y;
    h[6] = (_Float16)v1.z; h[7] = (_Float16)v1.w;
    return h;
}

// ---------- prep: V -> fp16 transposed Vt[b][h][d][m] ONLY (K/Q conversion
// is fused into qk_ln, deleting ~2/3 of this kernel from the serial prefix)
__global__ __launch_bounds__(256) void prep(
    const float* __restrict__ V, _Float16* __restrict__ Vt)
{
    __shared__ _Float16 tile[64][72];
    const int t = threadIdx.x;
    const int id = blockIdx.x;          // 512 blocks: 4b x 8h x 16 mtiles
    const int mt = id & 15, h = (id >> 4) & 7, b = id >> 7;
    const float4* Vf4 = (const float4*)V;
    for (int it = 0; it < 4; ++it) {
        const int ml = (t >> 4) + 16 * it;
        const int c4 = t & 15;
        float4 v = Vf4[(size_t)(b * 1024 + mt * 64 + ml) * 128 + h * 16 + c4];
        tile[c4 * 4 + 0][ml] = (_Float16)v.x;
        tile[c4 * 4 + 1][ml] = (_Float16)v.y;
        tile[c4 * 4 + 2][ml] = (_Float16)v.z;
        tile[c4 * 4 + 3][ml] = (_Float16)v.w;
    }
    __syncthreads();
    const int d = t >> 2, seg = t & 3;
    half8 o0 = *(half8*)&tile[d][seg * 16];
    half8 o1 = *(half8*)&tile[d][seg * 16 + 8];
    size_t obase = ((size_t)(b * 8 + h) * 64 + d) * 1024 + mt * 64 + seg * 16;
    *(half8*)&Vt[obase] = o0;
    *(half8*)&Vt[obase + 8] = o1;
}

// ---------- qk_ln: e = exp(LN(K.Q^T) - M) via fp16 MFMA, masked, stored to
// the Q-TILED S via LDS. r10/r13/r15 proven structure (mt=2, 8-way m-split,
// 4 blocks/CU, two-axis mask skip, dense 4KB stores); K/Q are now read as
// fp32 DIRECTLY from the kernel inputs with per-fragment conversion
// (identical rounding to the deleted prep pass -> bitwise-same outputs).
// M = max_h(2.8285*|gamma_h|+|beta_h|) bounds LN output, so exp never
// overflows without a per-row max pass.
__global__ __launch_bounds__(256) void qk_ln(
    const float* __restrict__ K, const float* __restrict__ Q,
    const float* __restrict__ gamma, const float* __restrict__ beta,
    const float* __restrict__ doc,
    _Float16* __restrict__ S, float* __restrict__ spart)
{
    __shared__ _Float16 se[128 * QK_PITCH];   // 34,816 B
    __shared__ float sf[128][4];              //  2,048 B -> 36.9 KB total

    const int t  = threadIdx.x;
    const int bi = blockIdx.x;              // 2048 = 4b x 64 lt x 8 q
    const int b  = bi & 3;
    const int lt = (bi >> 2) & 63;
    const int q  = bi >> 8;                 // 0..7, 128 m each
    const int wv = t >> 6, lane = t & 63;
    const int col = lane & 15, quad = lane >> 4;
    const int len = (int)doc[b];
    const int lbase = lt * 16;

    // all 16 rows masked -> nothing downstream ever reads this block's data
    if (lbase >= len) return;

    // entire m-range masked -> e == 0 everywhere; provide spart zeros, done.
    if (q * 128 >= len) {
        if (t < 128) {
            const int h = t >> 4, ll = t & 15;
            spart[((size_t)((b * 8 + h) * 1024 + lbase + ll)) * 8 + q] = 0.f;
        }
        return;
    }

    float g[8], be[8], M = 0.f;
    #pragma unroll
    for (int h = 0; h < 8; ++h) {
        g[h] = gamma[h]; be[h] = beta[h];
        M = fmaxf(M, 2.8285f * fabsf(g[h]) + fabsf(be[h]));
    }

    const float* Kb = K + (size_t)b * 524288;
    const float* Qb = Q + (size_t)b * 524288;
    const size_t krow = (size_t)(lbase + col) * 512;

    half8 a0[8], a1[8];
    #pragma unroll
    for (int h = 0; h < 8; ++h) {
        a0[h] = ldcvt8(&Kb[krow + h * 64 + quad * 8]);
        a1[h] = ldcvt8(&Kb[krow + h * 64 + 32 + quad * 8]);
    }

    float sum[8][4];
    #pragma unroll
    for (int h = 0; h < 8; ++h)
        #pragma unroll
        for (int r = 0; r < 4; ++r) sum[h][r] = 0.f;

    for (int mt = 0; mt < 2; ++mt) {
        const int m0 = q * 128 + wv * 32 + mt * 16;
        const size_t qrow = (size_t)(m0 + col) * 512;
        floatx4 c[8];
        #pragma unroll
        for (int h = 0; h < 8; ++h) {
            half8 b0 = ldcvt8(&Qb[qrow + h * 64 + quad * 8]);
            half8 b1 = ldcvt8(&Qb[qrow + h * 64 + 32 + quad * 8]);
            floatx4 z = {0.f, 0.f, 0.f, 0.f};
            z    = __builtin_amdgcn_mfma_f32_16x16x32_f16(a0[h], b0, z, 0, 0, 0);
            c[h] = __builtin_amdgcn_mfma_f32_16x16x32_f16(a1[h], b1, z, 0, 0, 0);
        }
        const bool mok = (m0 + col) < len;
        #pragma unroll
        for (int r = 0; r < 4; ++r) {
            const int l = lbase + quad * 4 + r;
            float mu = 0.f;
            #pragma unroll
            for (int h = 0; h < 8; ++h) mu += c[h][r];
            mu *= 0.125f;
            float var = 0.f;
            #pragma unroll
            for (int h = 0; h < 8; ++h) { float dd = c[h][r] - mu; var += dd * dd; }
            var *= 0.125f;
            const float rs = 1.0f / sqrtf(var + 1e-5f);
            const bool keep = mok && (l < len);
            #pragma unroll
            for (int h = 0; h < 8; ++h) {
                float e = 0.f;
                if (keep) {
                    float val = (c[h][r] - mu) * rs * g[h] + be[h];
                    e = __expf(val - M);
                }
                sum[h][r] += e;
                se[(h * 16 + quad * 4 + r) * QK_PITCH + wv * 32 + mt * 16 + col] =
                    (_Float16)e;
            }
        }
    }

    // reduce row partial sums over the 16 col-lanes of each quad; stash in sf
    #pragma unroll
    for (int h = 0; h < 8; ++h)
        #pragma unroll
        for (int r = 0; r < 4; ++r) {
            float s = sum[h][r];
            s += __shfl_xor(s, 1); s += __shfl_xor(s, 2);
            s += __shfl_xor(s, 4); s += __shfl_xor(s, 8);
            sum[h][r] = s;
        }
    if (col == 0) {
        #pragma unroll
        for (int h = 0; h < 8; ++h)
            #pragma unroll
            for (int r = 0; r < 4; ++r)
                sf[h * 16 + quad * 4 + r][wv] = sum[h][r];
    }
    __syncthreads();

    // store: per it (= one head), 16 rows x 256 B = ONE DENSE 4KB REGION
    #pragma unroll
    for (int it = 0; it < 8; ++it) {
        const int rr = it * 16 + (t >> 4);
        const int h = rr >> 4, l = rr & 15;
        half8 v = *(half8*)&se[rr * QK_PITCH + (t & 15) * 8];
        *(half8*)&S[((size_t)(b * 8 + h) << 20) + (size_t)q * 131072
                    + (size_t)(lbase + l) * 128 + (t & 15) * 8] = v;
    }

    // block-local wave reduction -> one spart slot per (row, q)
    if (t < 128) {
        const float s = sf[t][0] + sf[t][1] + sf[t][2] + sf[t][3];
        const int h = t >> 4, ll = t & 15;
        spart[((size_t)((b * 8 + h) * 1024 + lbase + ll)) * 8 + q] = s;
    }
}

// ---------- pv: fused PV + colsum over the Q-TILED S, two-axis mask skip.
// (r15 best-measured form: cs planes + wacc atomics.) MFMA consumes raw
// fp16 e (inv in the epilogue); scaled p feeds the shuffle-tree colsum.
// 8 waves, 8-deep e-ring + Vt ping-pong.
__global__ __launch_bounds__(512) void pv(
    const _Float16* __restrict__ S, const _Float16* __restrict__ Vt,
    const float* __restrict__ spart, const float* __restrict__ doc,
    float* __restrict__ out, float* __restrict__ wacc)
{
    __shared__ float inv_s[64];
    __shared__ float cs[4][1024];       // 16 KB, per-lg colsum planes
    __shared__ float comb[4][64][20];   // 20 KB

    const int t = threadIdx.x, wv = t >> 6, lane = t & 63;
    const int col = lane & 15, quad = lane >> 4;
    const int bi = blockIdx.x;            // 512 = 4b x 8h x 16 lb
    const int lb = bi & 15, h = (bi >> 4) & 7, b = bi >> 7;
    const int lg = wv & 3, mh = wv >> 2;
    const int l0 = lb * 64 + lg * 16;
    const size_t rbase = (size_t)(b * 8 + h) * 1024 + lb * 64;
    const int len = (int)doc[b];

    // zero colsum planes (skipped m-slots / skipped waves must contribute 0)
    #pragma unroll
    for (int i = 0; i < 8; ++i) ((float*)cs)[t + 512 * i] = 0.f;

    if (t < 64) {
        float s = 0.f;
        #pragma unroll
        for (int j = 0; j < 8; ++j) s += spart[(rbase + t) * 8 + j];
        inv_s[t] = ((lb * 64 + t) < len && s > 0.f) ? 1.0f / s : 0.f;
    }
    __syncthreads();

    const float inv = inv_s[lg * 16 + col];

    const int lenh = len - mh * 512;
    int kcmax = (lenh >= 512) ? 16 : ((lenh <= 0) ? 0 : ((lenh + 31) >> 5));
    if (l0 >= len) kcmax = 0;   // whole wave's rows masked -> skip everything

    // per-lane base in the tiled S: bh plane + mh's first tile + row + quad
    const _Float16* Arow = S + ((size_t)(b * 8 + h) << 20)
                         + (size_t)(mh * 4) * 131072
                         + (size_t)(l0 + col) * 128 + quad * 8;
    const _Float16* Vb = Vt + (size_t)(b * 8 + h) * 65536 + (size_t)col * 1024
                       + quad * 8 + mh * 512;

    floatx4 acc[4] = {{0,0,0,0},{0,0,0,0},{0,0,0,0},{0,0,0,0}};

    half8 ebuf[8];
    #pragma unroll
    for (int i = 0; i < 8; ++i)
        if (i < kcmax)
            ebuf[i] = *(const half8*)&Arow[EOFF(i)];

    half8 va[4], vb2[4];
    if (kcmax > 0) {
        #pragma unroll
        for (int dt = 0; dt < 4; ++dt)
            va[dt] = *(const half8*)&Vb[(size_t)(dt * 16) * 1024];
    }

    #pragma unroll
    for (int kc = 0; kc < 16; kc += 2) {
        if (kc < kcmax) {
            // ---- even step: consume va, prefetch vb2 (kc+1)
            half8 e0 = ebuf[kc & 7];
            if (kc + 8 < kcmax)
                ebuf[kc & 7] = *(const half8*)&Arow[EOFF(kc + 8)];
            if (kc + 1 < kcmax) {
                #pragma unroll
                for (int dt = 0; dt < 4; ++dt)
                    vb2[dt] = *(const half8*)&Vb[(size_t)(dt * 16) * 1024 + (kc + 1) * 32];
            }

            #pragma unroll
            for (int dt = 0; dt < 4; ++dt)
                acc[dt] = __builtin_amdgcn_mfma_f32_16x16x32_f16(e0, va[dt], acc[dt], 0, 0, 0);

            {
                half8 a;
                #pragma unroll
                for (int j = 0; j < 8; ++j) a[j] = (_Float16)((float)e0[j] * inv);
                const int mbase = mh * 512 + kc * 32 + quad * 8;
                #pragma unroll
                for (int u = 0; u < 4; ++u) {
                    half2v p2 = { a[2 * u], a[2 * u + 1] };
                    int bits = *(int*)&p2;
                    #pragma unroll
                    for (int o = 1; o < 16; o <<= 1) {
                        int ob = __shfl_xor(bits, o);
                        half2v po = *(half2v*)&ob;
                        half2v pc = *(half2v*)&bits;
                        pc[0] = pc[0] + po[0]; pc[1] = pc[1] + po[1];
                        bits = *(int*)&pc;
                    }
                    if (col == 0) {
                        half2v pc = *(half2v*)&bits;
                        cs[lg][mbase + 2 * u]     = (float)pc[0];
                        cs[lg][mbase + 2 * u + 1] = (float)pc[1];
                    }
                }
            }
        }

        if (kc + 1 < kcmax) {
            // ---- odd step: consume vb2, prefetch va (kc+2)
            half8 e1 = ebuf[(kc + 1) & 7];
            if (kc + 9 < kcmax)
                ebuf[(kc + 1) & 7] = *(const half8*)&Arow[EOFF(kc + 9)];
            if (kc + 2 < kcmax) {
                #pragma unroll
                for (int dt = 0; dt < 4; ++dt)
                    va[dt] = *(const half8*)&Vb[(size_t)(dt * 16) * 1024 + (kc + 2) * 32];
            }

            #pragma unroll
            for (int dt = 0; dt < 4; ++dt)
                acc[dt] = __builtin_amdgcn_mfma_f32_16x16x32_f16(e1, vb2[dt], acc[dt], 0, 0, 0);

            {
                half8 a2;
                #pragma unroll
                for (int j = 0; j < 8; ++j) a2[j] = (_Float16)((float)e1[j] * inv);
                const int mbase = mh * 512 + (kc + 1) * 32 + quad * 8;
                #pragma unroll
                for (int u = 0; u < 4; ++u) {
                    half2v p2 = { a2[2 * u], a2[2 * u + 1] };
                    int bits = *(int*)&p2;
                    #pragma unroll
                    for (int o = 1; o < 16; o <<= 1) {
                        int ob = __shfl_xor(bits, o);
                        half2v po = *(half2v*)&ob;
                        half2v pc = *(half2v*)&bits;
                        pc[0] = pc[0] + po[0]; pc[1] = pc[1] + po[1];
                        bits = *(int*)&pc;
                    }
                    if (col == 0) {
                        half2v pc = *(half2v*)&bits;
                        cs[lg][mbase + 2 * u]     = (float)pc[0];
                        cs[lg][mbase + 2 * u + 1] = (float)pc[1];
                    }
                }
            }
        }
    }

    if (mh == 1) {
        #pragma unroll
        for (int dt = 0; dt < 4; ++dt)
            *(floatx4*)&comb[lg][lane][dt * 4] = acc[dt];
    }
    __syncthreads();   // orders comb writes AND all cs plane writes
    if (mh == 0) {
        #pragma unroll
        for (int dt = 0; dt < 4; ++dt)
            acc[dt] += *(floatx4*)&comb[lg][lane][dt * 4];
        #pragma unroll
        for (int r = 0; r < 4; ++r) {
            const int l = l0 + quad * 4 + r;
            const float ivr = inv_s[lg * 16 + quad * 4 + r];
            float* orow = out + (size_t)(b * 1024 + l) * 512 + h * 64;
            #pragma unroll
            for (int dt = 0; dt < 4; ++dt)
                orow[dt * 16 + col] = acc[dt][r] * ivr;
        }
    }
    atomicAdd(&wacc[b * 1024 + t],
              cs[0][t] + cs[1][t] + cs[2][t] + cs[3][t]);
    atomicAdd(&wacc[b * 1024 + t + 512],
              cs[0][t + 512] + cs[1][t + 512] + cs[2][t + 512] + cs[3][t + 512]);
}

// ---------- w finalize: w = softmax_m( (wacc/8)/len ), invalid -> 0
__global__ __launch_bounds__(256) void w_final(
    const float* __restrict__ wacc, const float* __restrict__ doc,
    float* __restrict__ wout)
{
    const int b = blockIdx.x;
    const int t = threadIdx.x;
    __shared__ float red[4];

    const float ds = doc[b];
    const int len = (int)ds;

    float v[4];
    float mx = -INFINITY;
    #pragma unroll
    for (int i = 0; i < 4; ++i) {
        const int m = t + 256 * i;
        const float raw = wacc[b * L_ + m];
        v[i] = (m < len) ? (raw * 0.125f) / ds : -INFINITY;
        mx = fmaxf(mx, v[i]);
    }
    #pragma unroll
    for (int off = 1; off < 64; off <<= 1) mx = fmaxf(mx, __shfl_xor(mx, off));
    if ((t & 63) == 0) red[t >> 6] = mx;
    __syncthreads();
    mx = fmaxf(fmaxf(red[0], red[1]), fmaxf(red[2], red[3]));

    float e[4];
    float sm = 0.f;
    #pragma unroll
    for (int i = 0; i < 4; ++i) {
        e[i] = (v[i] != -INFINITY) ? __expf(v[i] - mx) : 0.f;
        sm += e[i];
    }
    #pragma unroll
    for (int off = 1; off < 64; off <<= 1) sm += __shfl_xor(sm, off);
    __syncthreads();
    if ((t & 63) == 0) red[t >> 6] = sm;
    __syncthreads();
    sm = red[0] + red[1] + red[2] + red[3];
    const float inv = (sm > 0.f) ? 1.0f / sm : 0.f;

    #pragma unroll
    for (int i = 0; i < 4; ++i)
        wout[b * L_ + t + 256 * i] = e[i] * inv;
}

extern "C" void kernel_launch(void* const* d_in, const int* in_sizes, int n_in,
                              void* d_out, int out_size, void* d_ws, size_t ws_size,
                              hipStream_t stream)
{
    const float* K     = (const float*)d_in[0];
    const float* Q     = (const float*)d_in[1];
    const float* V     = (const float*)d_in[2];
    const float* doc   = (const float*)d_in[3];
    const float* gamma = (const float*)d_in[4];
    const float* beta  = (const float*)d_in[5];

    float* out  = (float*)d_out;
    float* wout = out + (size_t)4 * L_ * D_;

    _Float16* S    = (_Float16*)d_ws;               // 64 MB (e-values, q-tiled)
    _Float16* Vt   = S + (size_t)33554432;          // +4 MB
    float*    spart = (float*)(Vt + 2097152);       // 1 MB (32768 x 8)
    float*    wacc  = spart + 262144;               // 16 KB

    hipMemsetAsync(wacc, 0, 4096 * sizeof(float), stream);
    prep   <<<dim3(512),  dim3(256), 0, stream>>>(V, Vt);
    qk_ln  <<<dim3(2048), dim3(256), 0, stream>>>(K, Q, gamma, beta, doc, S, spart);
    pv     <<<dim3(512),  dim3(512), 0, stream>>>(S, Vt, spart, doc, out, wacc);
    w_final<<<dim3(4),    dim3(256), 0, stream>>>(wacc, doc, wout);
}

// Round 18
// 181.871 us; speedup vs baseline: 1.2202x; 1.2202x over previous
//
#include <hip/hip_runtime.h>
#include <math.h>

// B=4, L=1024, D=512, H=8, d=64
#define L_ 1024
#define D_ 512

typedef _Float16 half8 __attribute__((ext_vector_type(8)));
typedef _Float16 half4v __attribute__((ext_vector_type(4)));
typedef _Float16 half2v __attribute__((ext_vector_type(2)));
typedef float floatx4 __attribute__((ext_vector_type(4)));

#define QK_PITCH 136   // halves/row (272B): proven conflict-free residue (r10)

// S layout is Q-TILED: S[bh(32)][q(8)][l(1024)][mi(128)] (halves)
//   addr = bh<<20 | q*131072 + l*128 + mi      (m = q*128 + mi)
// qk_ln's per-block store region per head = 16 consecutive l-rows x 256B
// = one DENSE 4KB block. pv chunk offsets are compile-time: EOFF(kc).
#define EOFF(kc) ((size_t)((kc) >> 2) * 131072 + (size_t)(((kc) & 3) * 32))

// ---------- prep: K,Q -> fp16 straight; V -> fp16 transposed Vt[b][h][d][m]
__global__ __launch_bounds__(256) void prep(
    const float* __restrict__ K, const float* __restrict__ Q,
    const float* __restrict__ V,
    _Float16* __restrict__ K16, _Float16* __restrict__ Q16,
    _Float16* __restrict__ Vt)
{
    __shared__ _Float16 tile[64][72];
    const int t = threadIdx.x;
    const int bi = blockIdx.x;
    if (bi < 2048) {
        #pragma unroll
        for (int it = 0; it < 2; ++it) {
            size_t f = (size_t)bi * 512 + it * 256 + t;
            const float4* src; _Float16* dst;
            if (f < 524288) { src = (const float4*)K; dst = K16; }
            else            { src = (const float4*)Q; dst = Q16; f -= 524288; }
            float4 v = src[f];
            half4v h = { (_Float16)v.x, (_Float16)v.y, (_Float16)v.z, (_Float16)v.w };
            *(half4v*)&dst[f * 4] = h;
        }
    } else {
        const int id = bi - 2048;           // 512 blocks: 4b x 8h x 16 mtiles
        const int mt = id & 15, h = (id >> 4) & 7, b = id >> 7;
        const float4* Vf4 = (const float4*)V;
        for (int it = 0; it < 4; ++it) {
            const int ml = (t >> 4) + 16 * it;
            const int c4 = t & 15;
            float4 v = Vf4[(size_t)(b * 1024 + mt * 64 + ml) * 128 + h * 16 + c4];
            tile[c4 * 4 + 0][ml] = (_Float16)v.x;
            tile[c4 * 4 + 1][ml] = (_Float16)v.y;
            tile[c4 * 4 + 2][ml] = (_Float16)v.z;
            tile[c4 * 4 + 3][ml] = (_Float16)v.w;
        }
        __syncthreads();
        const int d = t >> 2, seg = t & 3;
        half8 o0 = *(half8*)&tile[d][seg * 16];
        half8 o1 = *(half8*)&tile[d][seg * 16 + 8];
        size_t obase = ((size_t)(b * 8 + h) * 64 + d) * 1024 + mt * 64 + seg * 16;
        *(half8*)&Vt[obase] = o0;
        *(half8*)&Vt[obase + 8] = o1;
    }
}

// ---------- qk_ln: e = exp(LN(K.Q^T) - M) via fp16 MFMA, masked, stored to
// the Q-TILED S via LDS. r10/r13/r14/r15 proven structure (mt=2, 8-way
// m-split, VGPR~80, 4 blocks/CU, two-axis mask skip, dense 4KB stores).
// M = max_h(2.8285*|gamma_h|+|beta_h|) bounds LN output, so exp never
// overflows without a per-row max pass.
__global__ __launch_bounds__(256) void qk_ln(
    const _Float16* __restrict__ K16, const _Float16* __restrict__ Q16,
    const float* __restrict__ gamma, const float* __restrict__ beta,
    const float* __restrict__ doc,
    _Float16* __restrict__ S, float* __restrict__ spart)
{
    __shared__ _Float16 se[128 * QK_PITCH];   // 34,816 B
    __shared__ float sf[128][4];              //  2,048 B -> 36.9 KB total

    const int t  = threadIdx.x;
    const int bi = blockIdx.x;              // 2048 = 4b x 64 lt x 8 q
    const int b  = bi & 3;
    const int lt = (bi >> 2) & 63;
    const int q  = bi >> 8;                 // 0..7, 128 m each
    const int wv = t >> 6, lane = t & 63;
    const int col = lane & 15, quad = lane >> 4;
    const int len = (int)doc[b];
    const int lbase = lt * 16;

    // all 16 rows masked -> nothing downstream ever reads this block's data
    if (lbase >= len) return;

    // entire m-range masked -> e == 0 everywhere; provide spart zeros, done.
    if (q * 128 >= len) {
        if (t < 128) {
            const int h = t >> 4, ll = t & 15;
            spart[((size_t)((b * 8 + h) * 1024 + lbase + ll)) * 8 + q] = 0.f;
        }
        return;
    }

    float g[8], be[8], M = 0.f;
    #pragma unroll
    for (int h = 0; h < 8; ++h) {
        g[h] = gamma[h]; be[h] = beta[h];
        M = fmaxf(M, 2.8285f * fabsf(g[h]) + fabsf(be[h]));
    }

    const _Float16* Kb = K16 + (size_t)b * 524288;
    const _Float16* Qb = Q16 + (size_t)b * 524288;
    const size_t krow = (size_t)(lbase + col) * 512;

    half8 a0[8], a1[8];
    #pragma unroll
    for (int h = 0; h < 8; ++h) {
        a0[h] = *(const half8*)&Kb[krow + h * 64 + quad * 8];
        a1[h] = *(const half8*)&Kb[krow + h * 64 + 32 + quad * 8];
    }

    float sum[8][4];
    #pragma unroll
    for (int h = 0; h < 8; ++h)
        #pragma unroll
        for (int r = 0; r < 4; ++r) sum[h][r] = 0.f;

    for (int mt = 0; mt < 2; ++mt) {
        const int m0 = q * 128 + wv * 32 + mt * 16;
        const size_t qrow = (size_t)(m0 + col) * 512;
        floatx4 c[8];
        #pragma unroll
        for (int h = 0; h < 8; ++h) {
            half8 b0 = *(const half8*)&Qb[qrow + h * 64 + quad * 8];
            half8 b1 = *(const half8*)&Qb[qrow + h * 64 + 32 + quad * 8];
            floatx4 z = {0.f, 0.f, 0.f, 0.f};
            z    = __builtin_amdgcn_mfma_f32_16x16x32_f16(a0[h], b0, z, 0, 0, 0);
            c[h] = __builtin_amdgcn_mfma_f32_16x16x32_f16(a1[h], b1, z, 0, 0, 0);
        }
        const bool mok = (m0 + col) < len;
        #pragma unroll
        for (int r = 0; r < 4; ++r) {
            const int l = lbase + quad * 4 + r;
            float mu = 0.f;
            #pragma unroll
            for (int h = 0; h < 8; ++h) mu += c[h][r];
            mu *= 0.125f;
            float var = 0.f;
            #pragma unroll
            for (int h = 0; h < 8; ++h) { float dd = c[h][r] - mu; var += dd * dd; }
            var *= 0.125f;
            const float rs = 1.0f / sqrtf(var + 1e-5f);
            const bool keep = mok && (l < len);
            #pragma unroll
            for (int h = 0; h < 8; ++h) {
                float e = 0.f;
                if (keep) {
                    float val = (c[h][r] - mu) * rs * g[h] + be[h];
                    e = __expf(val - M);
                }
                sum[h][r] += e;
                se[(h * 16 + quad * 4 + r) * QK_PITCH + wv * 32 + mt * 16 + col] =
                    (_Float16)e;
            }
        }
    }

    // reduce row partial sums over the 16 col-lanes of each quad; stash in sf
    #pragma unroll
    for (int h = 0; h < 8; ++h)
        #pragma unroll
        for (int r = 0; r < 4; ++r) {
            float s = sum[h][r];
            s += __shfl_xor(s, 1); s += __shfl_xor(s, 2);
            s += __shfl_xor(s, 4); s += __shfl_xor(s, 8);
            sum[h][r] = s;
        }
    if (col == 0) {
        #pragma unroll
        for (int h = 0; h < 8; ++h)
            #pragma unroll
            for (int r = 0; r < 4; ++r)
                sf[h * 16 + quad * 4 + r][wv] = sum[h][r];
    }
    __syncthreads();

    // store: per it (= one head), 16 rows x 256 B = ONE DENSE 4KB REGION
    #pragma unroll
    for (int it = 0; it < 8; ++it) {
        const int rr = it * 16 + (t >> 4);
        const int h = rr >> 4, l = rr & 15;
        half8 v = *(half8*)&se[rr * QK_PITCH + (t & 15) * 8];
        *(half8*)&S[((size_t)(b * 8 + h) << 20) + (size_t)q * 131072
                    + (size_t)(lbase + l) * 128 + (t & 15) * 8] = v;
    }

    // block-local wave reduction -> one spart slot per (row, q)
    if (t < 128) {
        const float s = sf[t][0] + sf[t][1] + sf[t][2] + sf[t][3];
        const int h = t >> 4, ll = t & 15;
        spart[((size_t)((b * 8 + h) * 1024 + lbase + ll)) * 8 + q] = s;
    }
}

// ---------- pv: fused PV + colsum over the Q-TILED S, two-axis mask skip.
// MFMA consumes raw fp16 e (inv applied in the epilogue); scaled p feeds
// the shuffle-tree colsum into per-lg cs planes (plain stores, summed in
// the epilogue, accumulated to wacc via atomics). 8 waves (lg = l-group,
// mh = m-half), 8-deep e-ring + Vt ping-pong.
__global__ __launch_bounds__(512) void pv(
    const _Float16* __restrict__ S, const _Float16* __restrict__ Vt,
    const float* __restrict__ spart, const float* __restrict__ doc,
    float* __restrict__ out, float* __restrict__ wacc)
{
    __shared__ float inv_s[64];
    __shared__ float cs[4][1024];       // 16 KB, per-lg colsum planes
    __shared__ float comb[4][64][20];   // 20 KB

    const int t = threadIdx.x, wv = t >> 6, lane = t & 63;
    const int col = lane & 15, quad = lane >> 4;
    const int bi = blockIdx.x;            // 512 = 4b x 8h x 16 lb
    const int lb = bi & 15, h = (bi >> 4) & 7, b = bi >> 7;
    const int lg = wv & 3, mh = wv >> 2;
    const int l0 = lb * 64 + lg * 16;
    const size_t rbase = (size_t)(b * 8 + h) * 1024 + lb * 64;
    const int len = (int)doc[b];

    // zero colsum planes (skipped m-slots / skipped waves must contribute 0)
    #pragma unroll
    for (int i = 0; i < 8; ++i) ((float*)cs)[t + 512 * i] = 0.f;

    if (t < 64) {
        float s = 0.f;
        #pragma unroll
        for (int j = 0; j < 8; ++j) s += spart[(rbase + t) * 8 + j];
        inv_s[t] = ((lb * 64 + t) < len && s > 0.f) ? 1.0f / s : 0.f;
    }
    __syncthreads();

    const float inv = inv_s[lg * 16 + col];

    const int lenh = len - mh * 512;
    int kcmax = (lenh >= 512) ? 16 : ((lenh <= 0) ? 0 : ((lenh + 31) >> 5));
    if (l0 >= len) kcmax = 0;   // whole wave's rows masked -> skip everything

    // per-lane base in the tiled S: bh plane + mh's first tile + row + quad
    const _Float16* Arow = S + ((size_t)(b * 8 + h) << 20)
                         + (size_t)(mh * 4) * 131072
                         + (size_t)(l0 + col) * 128 + quad * 8;
    const _Float16* Vb = Vt + (size_t)(b * 8 + h) * 65536 + (size_t)col * 1024
                       + quad * 8 + mh * 512;

    floatx4 acc[4] = {{0,0,0,0},{0,0,0,0},{0,0,0,0},{0,0,0,0}};

    half8 ebuf[8];
    #pragma unroll
    for (int i = 0; i < 8; ++i)
        if (i < kcmax)
            ebuf[i] = *(const half8*)&Arow[EOFF(i)];

    half8 va[4], vb2[4];
    if (kcmax > 0) {
        #pragma unroll
        for (int dt = 0; dt < 4; ++dt)
            va[dt] = *(const half8*)&Vb[(size_t)(dt * 16) * 1024];
    }

    #pragma unroll
    for (int kc = 0; kc < 16; kc += 2) {
        if (kc < kcmax) {
            // ---- even step: consume va, prefetch vb2 (kc+1)
            half8 e0 = ebuf[kc & 7];
            if (kc + 8 < kcmax)
                ebuf[kc & 7] = *(const half8*)&Arow[EOFF(kc + 8)];
            if (kc + 1 < kcmax) {
                #pragma unroll
                for (int dt = 0; dt < 4; ++dt)
                    vb2[dt] = *(const half8*)&Vb[(size_t)(dt * 16) * 1024 + (kc + 1) * 32];
            }

            #pragma unroll
            for (int dt = 0; dt < 4; ++dt)
                acc[dt] = __builtin_amdgcn_mfma_f32_16x16x32_f16(e0, va[dt], acc[dt], 0, 0, 0);

            {
                half8 a;
                #pragma unroll
                for (int j = 0; j < 8; ++j) a[j] = (_Float16)((float)e0[j] * inv);
                const int mbase = mh * 512 + kc * 32 + quad * 8;
                #pragma unroll
                for (int u = 0; u < 4; ++u) {
                    half2v p2 = { a[2 * u], a[2 * u + 1] };
                    int bits = *(int*)&p2;
                    #pragma unroll
                    for (int o = 1; o < 16; o <<= 1) {
                        int ob = __shfl_xor(bits, o);
                        half2v po = *(half2v*)&ob;
                        half2v pc = *(half2v*)&bits;
                        pc[0] = pc[0] + po[0]; pc[1] = pc[1] + po[1];
                        bits = *(int*)&pc;
                    }
                    if (col == 0) {
                        half2v pc = *(half2v*)&bits;
                        cs[lg][mbase + 2 * u]     = (float)pc[0];
                        cs[lg][mbase + 2 * u + 1] = (float)pc[1];
                    }
                }
            }
        }

        if (kc + 1 < kcmax) {
            // ---- odd step: consume vb2, prefetch va (kc+2)
            half8 e1 = ebuf[(kc + 1) & 7];
            if (kc + 9 < kcmax)
                ebuf[(kc + 1) & 7] = *(const half8*)&Arow[EOFF(kc + 9)];
            if (kc + 2 < kcmax) {
                #pragma unroll
                for (int dt = 0; dt < 4; ++dt)
                    va[dt] = *(const half8*)&Vb[(size_t)(dt * 16) * 1024 + (kc + 2) * 32];
            }

            #pragma unroll
            for (int dt = 0; dt < 4; ++dt)
                acc[dt] = __builtin_amdgcn_mfma_f32_16x16x32_f16(e1, vb2[dt], acc[dt], 0, 0, 0);

            {
                half8 a2;
                #pragma unroll
                for (int j = 0; j < 8; ++j) a2[j] = (_Float16)((float)e1[j] * inv);
                const int mbase = mh * 512 + (kc + 1) * 32 + quad * 8;
                #pragma unroll
                for (int u = 0; u < 4; ++u) {
                    half2v p2 = { a2[2 * u], a2[2 * u + 1] };
                    int bits = *(int*)&p2;
                    #pragma unroll
                    for (int o = 1; o < 16; o <<= 1) {
                        int ob = __shfl_xor(bits, o);
                        half2v po = *(half2v*)&ob;
                        half2v pc = *(half2v*)&bits;
                        pc[0] = pc[0] + po[0]; pc[1] = pc[1] + po[1];
                        bits = *(int*)&pc;
                    }
                    if (col == 0) {
                        half2v pc = *(half2v*)&bits;
                        cs[lg][mbase + 2 * u]     = (float)pc[0];
                        cs[lg][mbase + 2 * u + 1] = (float)pc[1];
                    }
                }
            }
        }
    }

    if (mh == 1) {
        #pragma unroll
        for (int dt = 0; dt < 4; ++dt)
            *(floatx4*)&comb[lg][lane][dt * 4] = acc[dt];
    }
    __syncthreads();   // orders comb writes AND all cs plane writes
    if (mh == 0) {
        #pragma unroll
        for (int dt = 0; dt < 4; ++dt)
            acc[dt] += *(floatx4*)&comb[lg][lane][dt * 4];
        #pragma unroll
        for (int r = 0; r < 4; ++r) {
            const int l = l0 + quad * 4 + r;
            const float ivr = inv_s[lg * 16 + quad * 4 + r];
            float* orow = out + (size_t)(b * 1024 + l) * 512 + h * 64;
            #pragma unroll
            for (int dt = 0; dt < 4; ++dt)
                orow[dt * 16 + col] = acc[dt][r] * ivr;
        }
    }
    atomicAdd(&wacc[b * 1024 + t],
              cs[0][t] + cs[1][t] + cs[2][t] + cs[3][t]);
    atomicAdd(&wacc[b * 1024 + t + 512],
              cs[0][t + 512] + cs[1][t + 512] + cs[2][t + 512] + cs[3][t + 512]);
}

// ---------- w finalize: w = softmax_m( (wacc/8)/len ), invalid -> 0
__global__ __launch_bounds__(256) void w_final(
    const float* __restrict__ wacc, const float* __restrict__ doc,
    float* __restrict__ wout)
{
    const int b = blockIdx.x;
    const int t = threadIdx.x;
    __shared__ float red[4];

    const float ds = doc[b];
    const int len = (int)ds;

    float v[4];
    float mx = -INFINITY;
    #pragma unroll
    for (int i = 0; i < 4; ++i) {
        const int m = t + 256 * i;
        const float raw = wacc[b * L_ + m];
        v[i] = (m < len) ? (raw * 0.125f) / ds : -INFINITY;
        mx = fmaxf(mx, v[i]);
    }
    #pragma unroll
    for (int off = 1; off < 64; off <<= 1) mx = fmaxf(mx, __shfl_xor(mx, off));
    if ((t & 63) == 0) red[t >> 6] = mx;
    __syncthreads();
    mx = fmaxf(fmaxf(red[0], red[1]), fmaxf(red[2], red[3]));

    float e[4];
    float sm = 0.f;
    #pragma unroll
    for (int i = 0; i < 4; ++i) {
        e[i] = (v[i] != -INFINITY) ? __expf(v[i] - mx) : 0.f;
        sm += e[i];
    }
    #pragma unroll
    for (int off = 1; off < 64; off <<= 1) sm += __shfl_xor(sm, off);
    __syncthreads();
    if ((t & 63) == 0) red[t >> 6] = sm;
    __syncthreads();
    sm = red[0] + red[1] + red[2] + red[3];
    const float inv = (sm > 0.f) ? 1.0f / sm : 0.f;

    #pragma unroll
    for (int i = 0; i < 4; ++i)
        wout[b * L_ + t + 256 * i] = e[i] * inv;
}

extern "C" void kernel_launch(void* const* d_in, const int* in_sizes, int n_in,
                              void* d_out, int out_size, void* d_ws, size_t ws_size,
                              hipStream_t stream)
{
    const float* K     = (const float*)d_in[0];
    const float* Q     = (const float*)d_in[1];
    const float* V     = (const float*)d_in[2];
    const float* doc   = (const float*)d_in[3];
    const float* gamma = (const float*)d_in[4];
    const float* beta  = (const float*)d_in[5];

    float* out  = (float*)d_out;
    float* wout = out + (size_t)4 * L_ * D_;

    _Float16* S    = (_Float16*)d_ws;               // 64 MB (e-values, q-tiled)
    _Float16* K16  = S + (size_t)33554432;          // +4 MB
    _Float16* Q16  = K16 + 2097152;                 // +4 MB
    _Float16* Vt   = Q16 + 2097152;                 // +4 MB
    float*    spart = (float*)(Vt + 2097152);       // 1 MB used (32768 x 8)
    float*    wacc  = spart + 524288 + 32768;       // 16 KB

    hipMemsetAsync(wacc, 0, 4096 * sizeof(float), stream);
    prep   <<<dim3(2560), dim3(256), 0, stream>>>(K, Q, V, K16, Q16, Vt);
    qk_ln  <<<dim3(2048), dim3(256), 0, stream>>>(K16, Q16, gamma, beta, doc, S, spart);
    pv     <<<dim3(512),  dim3(512), 0, stream>>>(S, Vt, spart, doc, out, wacc);
    w_final<<<dim3(4),    dim3(256), 0, stream>>>(wacc, doc, wout);
}